// Round 3
// baseline (1085.059 us; speedup 1.0000x reference)
//
#include <hip/hip_runtime.h>
#include <math.h>

// Problem constants (B=2, H=8, S=2048, D=64)
#define BH_    16          // B*H
#define S_     2048
#define D_     64
#define QT     4           // queries per block
#define BLOCK  256
#define KPT    8           // keys per thread in phase 1 = S_/BLOCK
#define NEWTON_ITERS 10

__device__ __forceinline__ float comp(const float4& a, int u) {
  return u == 0 ? a.x : u == 1 ? a.y : u == 2 ? a.z : a.w;
}

// __launch_bounds__(256,4): cap VGPR at 128 so 4 waves/SIMD co-reside.
// R1 evidence: without it VGPR=256 + 265MB spill traffic, occupancy 12%.
__global__ __launch_bounds__(BLOCK, 4)
void entmax_attn_kernel(const float* __restrict__ q,
                        const float* __restrict__ k,
                        const float* __restrict__ v,
                        float* __restrict__ out) {
  // sc: scores -> p -> (aliased) phase-4 partial sums. 32KB.
  __shared__ float sc[QT][S_];
  __shared__ float qs[QT][D_];

  const int t   = threadIdx.x;
  const int blk = blockIdx.x;
  const int bh  = blk >> 9;          // blk / (S_/QT)
  const int qt  = blk & 511;         // blk % (S_/QT)
  const size_t qoff = ((size_t)bh * S_ + (size_t)qt * QT) * D_;
  const float* qp = q + qoff;
  const float* kp = k + (size_t)bh * S_ * D_;
  const float* vp = v + (size_t)bh * S_ * D_;
  float* op = out + qoff;

  // ---- load q tile; fold scale (1/8) and the entmax /2 => *1/16
  ((float*)qs)[t] = qp[t] * 0.0625f;   // QT*D_ == BLOCK
  __syncthreads();

  // ---- phase 1: scores. dc-OUTER / key-INNER: q tile read from LDS once
  // per dc chunk (64 ds_read_b128/thread total vs 512 in R2); k addresses
  // are 8 hoisted row bases + immediate dc offsets (0 VALU per load).
  {
    float acc[QT][KPT];
#pragma unroll
    for (int qq = 0; qq < QT; ++qq)
#pragma unroll
      for (int j = 0; j < KPT; ++j) acc[qq][j] = 0.f;

    const float* kbase = kp + (size_t)t * D_;
#pragma unroll 1            // keep live set small: 16 q + 32 acc + 32 k-regs
    for (int dc = 0; dc < D_; dc += 4) {
      float4 q0 = *(const float4*)&qs[0][dc];
      float4 q1 = *(const float4*)&qs[1][dc];
      float4 q2 = *(const float4*)&qs[2][dc];
      float4 q3 = *(const float4*)&qs[3][dc];
#pragma unroll
      for (int j = 0; j < KPT; ++j) {
        float4 kv = *(const float4*)(kbase + (size_t)j * (BLOCK * D_) + dc);
        acc[0][j] = fmaf(q0.x, kv.x, acc[0][j]);
        acc[0][j] = fmaf(q0.y, kv.y, acc[0][j]);
        acc[0][j] = fmaf(q0.z, kv.z, acc[0][j]);
        acc[0][j] = fmaf(q0.w, kv.w, acc[0][j]);
        acc[1][j] = fmaf(q1.x, kv.x, acc[1][j]);
        acc[1][j] = fmaf(q1.y, kv.y, acc[1][j]);
        acc[1][j] = fmaf(q1.z, kv.z, acc[1][j]);
        acc[1][j] = fmaf(q1.w, kv.w, acc[1][j]);
        acc[2][j] = fmaf(q2.x, kv.x, acc[2][j]);
        acc[2][j] = fmaf(q2.y, kv.y, acc[2][j]);
        acc[2][j] = fmaf(q2.z, kv.z, acc[2][j]);
        acc[2][j] = fmaf(q2.w, kv.w, acc[2][j]);
        acc[3][j] = fmaf(q3.x, kv.x, acc[3][j]);
        acc[3][j] = fmaf(q3.y, kv.y, acc[3][j]);
        acc[3][j] = fmaf(q3.z, kv.z, acc[3][j]);
        acc[3][j] = fmaf(q3.w, kv.w, acc[3][j]);
      }
    }
#pragma unroll
    for (int j = 0; j < KPT; ++j) {
      const int kk = t + BLOCK * j;   // stride-1 across lanes: conflict-free
      sc[0][kk] = acc[0][j]; sc[1][kk] = acc[1][j];
      sc[2][kk] = acc[2][j]; sc[3][kk] = acc[3][j];
    }
  }
  __syncthreads();

  // ---- phase 2/3: one wave per query. Row max + Newton for tau, then p.
  {
    const int wave = t >> 6;        // query index 0..3
    const int lane = t & 63;
    float4 xv[8];                   // row cache: 32 VGPRs
#pragma unroll
    for (int i = 0; i < 8; ++i)
      xv[i] = *(const float4*)&sc[wave][lane * 4 + i * 256];

    float m = -1e30f;
#pragma unroll
    for (int i = 0; i < 8; ++i)
      m = fmaxf(m, fmaxf(fmaxf(xv[i].x, xv[i].y), fmaxf(xv[i].z, xv[i].w)));
#pragma unroll
    for (int off = 32; off >= 1; off >>= 1)
      m = fmaxf(m, __shfl_xor(m, off, 64));
#pragma unroll
    for (int i = 0; i < 8; ++i) {   // x = (z - max(z))/2, max now 0
      xv[i].x -= m; xv[i].y -= m; xv[i].z -= m; xv[i].w -= m;
    }

    // Newton on f(tau) = sum max(x - tau, 0)^2 - 1, from tau = -1 (monotone
    // from below; f is exactly quadratic once support stabilizes ->
    // quadratic convergence; 10 iters leaves tau error << fp32 roundoff).
    float tau = -1.0f;
    for (int it = 0; it < NEWTON_ITERS; ++it) {
      float s1 = 0.f, s2 = 0.f;
#pragma unroll
      for (int i = 0; i < 8; ++i) {
        float u0 = fmaxf(xv[i].x - tau, 0.f);
        float u1 = fmaxf(xv[i].y - tau, 0.f);
        float u2 = fmaxf(xv[i].z - tau, 0.f);
        float u3 = fmaxf(xv[i].w - tau, 0.f);
        s1 += (u0 + u1) + (u2 + u3);
        s2 = fmaf(u0, u0, s2); s2 = fmaf(u1, u1, s2);
        s2 = fmaf(u2, u2, s2); s2 = fmaf(u3, u3, s2);
      }
#pragma unroll
      for (int off = 32; off >= 1; off >>= 1) {
        s1 += __shfl_xor(s1, off, 64);
        s2 += __shfl_xor(s2, off, 64);
      }
      tau += (s2 - 1.0f) / (2.0f * s1);
    }

    // p = clip(x - tau, 0)^2, write back over scores
#pragma unroll
    for (int i = 0; i < 8; ++i) {
      float u0 = fmaxf(xv[i].x - tau, 0.f);
      float u1 = fmaxf(xv[i].y - tau, 0.f);
      float u2 = fmaxf(xv[i].z - tau, 0.f);
      float u3 = fmaxf(xv[i].w - tau, 0.f);
      float4 r; r.x = u0*u0; r.y = u1*u1; r.z = u2*u2; r.w = u3*u3;
      *(float4*)&sc[wave][lane * 4 + i * 256] = r;
    }
  }
  __syncthreads();

  // ---- phase 4: out = p @ v. 16 key-groups x 16 dim-lanes (float4 dims).
  {
    const int d4 = t & 15;          // float4 column within D
    const int g  = t >> 4;          // key group, 128 keys each
    // Bank derotation: the wave's 4 g-groups read sc addresses 512B apart
    // (bank-identical, 128%32==0) -> 4-way conflict (R1/R2: 2^24 conflicts,
    // all from here). Rotating each g's kb start by 4*g puts the four
    // 16B reads on disjoint bank quads {0,4,8,12}+kb. Exact (sum reorder).
    const int rot = (g << 2) & 127;
    const float4* v4 = (const float4*)vp;
    float4 acc0 = {0,0,0,0}, acc1 = {0,0,0,0}, acc2 = {0,0,0,0}, acc3 = {0,0,0,0};
    const int k0 = g * 128;
#pragma unroll 2
    for (int kb = 0; kb < 128; kb += 4) {
      const int kk = k0 + ((kb + rot) & 127);
      float4 p0 = *(const float4*)&sc[0][kk];
      float4 p1 = *(const float4*)&sc[1][kk];
      float4 p2 = *(const float4*)&sc[2][kk];
      float4 p3 = *(const float4*)&sc[3][kk];
      // entmax rows are sparse: skip 4-key blocks with zero support (exact).
      float ssum = (p0.x + p0.y + p0.z + p0.w) + (p1.x + p1.y + p1.z + p1.w)
                 + (p2.x + p2.y + p2.z + p2.w) + (p3.x + p3.y + p3.z + p3.w);
      if (ssum > 0.f) {
#pragma unroll
        for (int u = 0; u < 4; ++u) {
          float4 vv = v4[(size_t)(kk + u) * (D_ / 4) + d4];
          float c0 = comp(p0, u), c1 = comp(p1, u), c2 = comp(p2, u), c3 = comp(p3, u);
          acc0.x = fmaf(c0, vv.x, acc0.x); acc0.y = fmaf(c0, vv.y, acc0.y);
          acc0.z = fmaf(c0, vv.z, acc0.z); acc0.w = fmaf(c0, vv.w, acc0.w);
          acc1.x = fmaf(c1, vv.x, acc1.x); acc1.y = fmaf(c1, vv.y, acc1.y);
          acc1.z = fmaf(c1, vv.z, acc1.z); acc1.w = fmaf(c1, vv.w, acc1.w);
          acc2.x = fmaf(c2, vv.x, acc2.x); acc2.y = fmaf(c2, vv.y, acc2.y);
          acc2.z = fmaf(c2, vv.z, acc2.z); acc2.w = fmaf(c2, vv.w, acc2.w);
          acc3.x = fmaf(c3, vv.x, acc3.x); acc3.y = fmaf(c3, vv.y, acc3.y);
          acc3.z = fmaf(c3, vv.z, acc3.z); acc3.w = fmaf(c3, vv.w, acc3.w);
        }
      }
    }
    __syncthreads();                 // all p reads done; safe to overwrite sc
    float* red = &sc[0][0];          // red[g][qq][d] : 16*4*64 floats = 16KB
    *(float4*)&red[(g * QT + 0) * D_ + d4 * 4] = acc0;
    *(float4*)&red[(g * QT + 1) * D_ + d4 * 4] = acc1;
    *(float4*)&red[(g * QT + 2) * D_ + d4 * 4] = acc2;
    *(float4*)&red[(g * QT + 3) * D_ + d4 * 4] = acc3;
    __syncthreads();
    // final cross-group reduction: thread -> (qq, d)
    const int qq = t >> 6, d = t & 63;
    float sum = 0.f;
#pragma unroll
    for (int gg = 0; gg < 16; ++gg) sum += red[(gg * QT + qq) * D_ + d];
    op[qq * D_ + d] = sum;
  }
}

extern "C" void kernel_launch(void* const* d_in, const int* in_sizes, int n_in,
                              void* d_out, int out_size, void* d_ws, size_t ws_size,
                              hipStream_t stream) {
  const float* q = (const float*)d_in[0];
  const float* k = (const float*)d_in[1];
  const float* v = (const float*)d_in[2];
  float* out = (float*)d_out;
  dim3 grid(BH_ * (S_ / QT));   // 16 * 512 = 8192 blocks
  entmax_attn_kernel<<<grid, dim3(BLOCK), 0, stream>>>(q, k, v, out);
}

// Round 4
// 599.809 us; speedup vs baseline: 1.8090x; 1.8090x over previous
//
#include <hip/hip_runtime.h>
#include <math.h>

// Problem constants (B=2, H=8, S=2048, D=64)
#define BH_    16          // B*H
#define S_     2048
#define D_     64
#define QT     4           // queries per block
#define BLOCK  256
#define KPT    8           // keys per thread in phase 1 = S_/BLOCK
#define NEWTON_ITERS 10

__device__ __forceinline__ float comp(const float4& a, int u) {
  return u == 0 ? a.x : u == 1 ? a.y : u == 2 ? a.z : a.w;
}

// __launch_bounds__(256,4): cap VGPR at 128 so 4 waves/SIMD co-reside.
// R1 evidence: without it VGPR=256 + 265MB spill traffic, occupancy 12%.
__global__ __launch_bounds__(BLOCK, 4)
void entmax_attn_kernel(const float* __restrict__ q,
                        const float* __restrict__ k,
                        const float* __restrict__ v,
                        float* __restrict__ out) {
  // sc: scores -> p -> (aliased) phase-4 partial sums. 32KB. No q in LDS:
  // q is wave-uniform -> scalar loads (R2 evidence: 512 ds_read_b128/wave
  // on q re-reads = ~330us of LDS-pipe time, the dominant cost).
  __shared__ float sc[QT][S_];

  const int t   = threadIdx.x;
  const int blk = blockIdx.x;
  const int bh  = blk >> 9;          // blk / (S_/QT)
  const int qt  = blk & 511;         // blk % (S_/QT)
  const size_t qoff = ((size_t)bh * S_ + (size_t)qt * QT) * D_;
  const float* qp = q + qoff;
  const float* kp = k + (size_t)bh * S_ * D_;
  const float* vp = v + (size_t)bh * S_ * D_;
  float* op = out + qoff;

  // ---- phase 1: scores. Key-outer (R2's contiguous k streaming: R3's
  // dc-outer form thrashed L1 and serialized loads -> 1085us). q read via
  // uniform (scalar) loads, consumed directly as the 1 allowed SGPR operand
  // of v_fmac. Scale (1/8 * entmax /2 = 1/16) applied at score store.
  for (int j = 0; j < KPT; ++j) {
    const float* krow = kp + (size_t)(t + BLOCK * j) * D_;
    float a[QT] = {0.f, 0.f, 0.f, 0.f};
#pragma unroll
    for (int dc = 0; dc < D_; dc += 4) {
      float4 kv = *(const float4*)(krow + dc);
#pragma unroll
      for (int qq = 0; qq < QT; ++qq) {
        a[qq] = fmaf(qp[qq * D_ + dc + 0], kv.x, a[qq]);
        a[qq] = fmaf(qp[qq * D_ + dc + 1], kv.y, a[qq]);
        a[qq] = fmaf(qp[qq * D_ + dc + 2], kv.z, a[qq]);
        a[qq] = fmaf(qp[qq * D_ + dc + 3], kv.w, a[qq]);
      }
    }
    const int kk = t + BLOCK * j;   // stride-1 across lanes: conflict-free
    sc[0][kk] = a[0] * 0.0625f;
    sc[1][kk] = a[1] * 0.0625f;
    sc[2][kk] = a[2] * 0.0625f;
    sc[3][kk] = a[3] * 0.0625f;
  }
  __syncthreads();

  // ---- phase 2/3: one wave per query. Row max + Newton for tau, then p.
  {
    const int wave = t >> 6;        // query index 0..3
    const int lane = t & 63;
    float4 xv[8];                   // row cache: 32 VGPRs
#pragma unroll
    for (int i = 0; i < 8; ++i)
      xv[i] = *(const float4*)&sc[wave][lane * 4 + i * 256];

    float m = -1e30f;
#pragma unroll
    for (int i = 0; i < 8; ++i)
      m = fmaxf(m, fmaxf(fmaxf(xv[i].x, xv[i].y), fmaxf(xv[i].z, xv[i].w)));
#pragma unroll
    for (int off = 32; off >= 1; off >>= 1)
      m = fmaxf(m, __shfl_xor(m, off, 64));
#pragma unroll
    for (int i = 0; i < 8; ++i) {   // x = (z - max(z))/2, max now 0
      xv[i].x -= m; xv[i].y -= m; xv[i].z -= m; xv[i].w -= m;
    }

    // Newton on f(tau) = sum max(x - tau, 0)^2 - 1, from tau = -1 (monotone
    // from below; f is exactly quadratic once support stabilizes ->
    // quadratic convergence; 10 iters leaves tau error << fp32 roundoff).
    float tau = -1.0f;
    for (int it = 0; it < NEWTON_ITERS; ++it) {
      float s1 = 0.f, s2 = 0.f;
#pragma unroll
      for (int i = 0; i < 8; ++i) {
        float u0 = fmaxf(xv[i].x - tau, 0.f);
        float u1 = fmaxf(xv[i].y - tau, 0.f);
        float u2 = fmaxf(xv[i].z - tau, 0.f);
        float u3 = fmaxf(xv[i].w - tau, 0.f);
        s1 += (u0 + u1) + (u2 + u3);
        s2 = fmaf(u0, u0, s2); s2 = fmaf(u1, u1, s2);
        s2 = fmaf(u2, u2, s2); s2 = fmaf(u3, u3, s2);
      }
#pragma unroll
      for (int off = 32; off >= 1; off >>= 1) {
        s1 += __shfl_xor(s1, off, 64);
        s2 += __shfl_xor(s2, off, 64);
      }
      tau += (s2 - 1.0f) / (2.0f * s1);
    }

    // p = clip(x - tau, 0)^2, write back over scores
#pragma unroll
    for (int i = 0; i < 8; ++i) {
      float u0 = fmaxf(xv[i].x - tau, 0.f);
      float u1 = fmaxf(xv[i].y - tau, 0.f);
      float u2 = fmaxf(xv[i].z - tau, 0.f);
      float u3 = fmaxf(xv[i].w - tau, 0.f);
      float4 r; r.x = u0*u0; r.y = u1*u1; r.z = u2*u2; r.w = u3*u3;
      *(float4*)&sc[wave][lane * 4 + i * 256] = r;
    }
  }
  __syncthreads();

  // ---- phase 4: out = p @ v. 16 key-groups x 16 dim-lanes (float4 dims).
  {
    const int d4 = t & 15;          // float4 column within D
    const int g  = t >> 4;          // key group, 128 keys each
    // Bank derotation (R3: conflicts 1.678e7 -> 0): rotate each g's kb
    // start by 4*g so the wave's four g-groups hit disjoint bank quads.
    const int rot = (g << 2) & 127;
    const float4* v4 = (const float4*)vp;
    float4 acc0 = {0,0,0,0}, acc1 = {0,0,0,0}, acc2 = {0,0,0,0}, acc3 = {0,0,0,0};
    const int k0 = g * 128;
#pragma unroll 2
    for (int kb = 0; kb < 128; kb += 4) {
      const int kk = k0 + ((kb + rot) & 127);
      float4 p0 = *(const float4*)&sc[0][kk];
      float4 p1 = *(const float4*)&sc[1][kk];
      float4 p2 = *(const float4*)&sc[2][kk];
      float4 p3 = *(const float4*)&sc[3][kk];
      // entmax rows are sparse: skip 4-key blocks with zero support (exact).
      float ssum = (p0.x + p0.y + p0.z + p0.w) + (p1.x + p1.y + p1.z + p1.w)
                 + (p2.x + p2.y + p2.z + p2.w) + (p3.x + p3.y + p3.z + p3.w);
      if (ssum > 0.f) {
#pragma unroll
        for (int u = 0; u < 4; ++u) {
          float4 vv = v4[(size_t)(kk + u) * (D_ / 4) + d4];
          float c0 = comp(p0, u), c1 = comp(p1, u), c2 = comp(p2, u), c3 = comp(p3, u);
          acc0.x = fmaf(c0, vv.x, acc0.x); acc0.y = fmaf(c0, vv.y, acc0.y);
          acc0.z = fmaf(c0, vv.z, acc0.z); acc0.w = fmaf(c0, vv.w, acc0.w);
          acc1.x = fmaf(c1, vv.x, acc1.x); acc1.y = fmaf(c1, vv.y, acc1.y);
          acc1.z = fmaf(c1, vv.z, acc1.z); acc1.w = fmaf(c1, vv.w, acc1.w);
          acc2.x = fmaf(c2, vv.x, acc2.x); acc2.y = fmaf(c2, vv.y, acc2.y);
          acc2.z = fmaf(c2, vv.z, acc2.z); acc2.w = fmaf(c2, vv.w, acc2.w);
          acc3.x = fmaf(c3, vv.x, acc3.x); acc3.y = fmaf(c3, vv.y, acc3.y);
          acc3.z = fmaf(c3, vv.z, acc3.z); acc3.w = fmaf(c3, vv.w, acc3.w);
        }
      }
    }
    __syncthreads();                 // all p reads done; safe to overwrite sc
    float* red = &sc[0][0];          // red[g][qq][d] : 16*4*64 floats = 16KB
    *(float4*)&red[(g * QT + 0) * D_ + d4 * 4] = acc0;
    *(float4*)&red[(g * QT + 1) * D_ + d4 * 4] = acc1;
    *(float4*)&red[(g * QT + 2) * D_ + d4 * 4] = acc2;
    *(float4*)&red[(g * QT + 3) * D_ + d4 * 4] = acc3;
    __syncthreads();
    // final cross-group reduction: thread -> (qq, d)
    const int qq = t >> 6, d = t & 63;
    float sum = 0.f;
#pragma unroll
    for (int gg = 0; gg < 16; ++gg) sum += red[(gg * QT + qq) * D_ + d];
    op[qq * D_ + d] = sum;
  }
}

extern "C" void kernel_launch(void* const* d_in, const int* in_sizes, int n_in,
                              void* d_out, int out_size, void* d_ws, size_t ws_size,
                              hipStream_t stream) {
  const float* q = (const float*)d_in[0];
  const float* k = (const float*)d_in[1];
  const float* v = (const float*)d_in[2];
  float* out = (float*)d_out;
  dim3 grid(BH_ * (S_ / QT));   // 16 * 512 = 8192 blocks
  entmax_attn_kernel<<<grid, dim3(BLOCK), 0, stream>>>(q, k, v, out);
}